// Round 4
// baseline (95.029 us; speedup 1.0000x reference)
//
#include <hip/hip_runtime.h>

#define NROWS 8192
#define DIMX  128          // raw feature dims
#define DIM2  160          // padded K: 128 data + 1 sq-dim + 10 one-hot + 21 zero
#define NCLS  10
#define GAPV  0.4f
#define BIAS  2048.0f      // 2 * 32 * 32
#define C0    128.0f       // sq centering constant
#define CHUNK 512          // cols per block
#define NCHUNK (NROWS / CHUNK)   // 16 blocks per rowgroup
#define NRG    (NROWS / 256)     // 32 rowgroups
#define SLAB  32           // cols staged per LDS buffer
#define NSLAB (CHUNK / SLAB)
#define LDST  168          // LDS row stride in shorts (336B: 16B-aligned, 2-way bank = free)

typedef __attribute__((ext_vector_type(8))) short bf16x8;
typedef __attribute__((ext_vector_type(4))) float f32x4;

// monotone float <-> uint encoding so atomicMax/atomicMin on uint order like floats
__device__ __forceinline__ unsigned fenc(float f) {
  unsigned u = __float_as_uint(f);
  return (u & 0x80000000u) ? ~u : (u | 0x80000000u);
}
__device__ __forceinline__ float fdec(unsigned u) {
  return (u & 0x80000000u) ? __uint_as_float(u & 0x7fffffffu) : __uint_as_float(~u);
}
__device__ __forceinline__ short f2bf(float f) {  // RNE fp32->bf16
  unsigned u = __float_as_uint(f);
  u += 0x7fffu + ((u >> 16) & 1u);
  return (short)(u >> 16);
}

// ---- kernel 1: build augmented bf16 arrays, sq, init accumulators, confusion, zero counters ----
// xa[row]  = [bf16(x), 1.0,         +32*onehot(cls), 0...]   (A operand)
// xbm[row] = [bf16(x), -(sq-128)/2, -32*onehot(cls), 0...]   (B operand)
// => g = dot(xa_i, xbm_j) = dot_ij - (sq_j-128)/2 - 1024*[same]
//    h = 128 - 2g = sq_j - 2dot + 2048*[same]
__global__ __launch_bounds__(256) void prep_k(const float* __restrict__ x,
                                              const int* __restrict__ tgt,
                                              const float* __restrict__ pred,
                                              short* __restrict__ xa,
                                              short* __restrict__ xbm,
                                              float* __restrict__ sq,
                                              unsigned* __restrict__ emax,
                                              unsigned* __restrict__ emin,
                                              int* __restrict__ conf,
                                              unsigned* __restrict__ ctrs) {
  if (blockIdx.x == 0 && threadIdx.x < NRG + 3) ctrs[threadIdx.x] = 0u;  // rg_done[32], g_done, Ssum, Csum

  const int wave = threadIdx.x >> 6;
  const int lane = threadIdx.x & 63;
  const int row  = blockIdx.x * 4 + wave;
  const float* p = x + (size_t)row * DIMX;
  const float a = p[lane];
  const float b = p[lane + 64];
  float s = a * a + b * b;
  #pragma unroll
  for (int m = 1; m < 64; m <<= 1) s += __shfl_xor(s, m, 64);

  short* pa = xa  + (size_t)row * DIM2;
  short* pb = xbm + (size_t)row * DIM2;
  pa[lane] = f2bf(a); pa[lane + 64] = f2bf(b);
  pb[lane] = f2bf(a); pb[lane + 64] = f2bf(b);

  const int cls = tgt[row];
  if (lane < 32) {
    short va, vb;
    if (lane == 0)          { va = (short)0x3F80; vb = f2bf(-0.5f * (s - C0)); }
    else if (lane <= NCLS)  { const bool hit = (lane - 1) == cls;
                              va = hit ? (short)0x4200 : (short)0;
                              vb = hit ? (short)0xC200 : (short)0; }
    else                    { va = 0; vb = 0; }
    pa[128 + lane] = va;
    pb[128 + lane] = vb;
  }

  if (lane == 0) {
    sq[row]   = s;
    emax[row] = fenc(-INFINITY);
    emin[row] = fenc(INFINITY);
    const float* pp = pred + (size_t)row * NCLS;
    float v[NCLS];
    #pragma unroll
    for (int c = 0; c < NCLS; ++c) v[c] = pp[c];
    float m1 = v[0]; int i1 = 0;
    #pragma unroll
    for (int c = 1; c < NCLS; ++c)
      if (v[c] > m1) { m1 = v[c]; i1 = c; }
    float m2 = -INFINITY, sum = 0.f;
    #pragma unroll
    for (int c = 0; c < NCLS; ++c) {
      sum += __expf(v[c] - m1);
      if (c != i1) m2 = fmaxf(m2, v[c]);
    }
    const float d01 = (1.f - __expf(m2 - m1)) / sum;
    conf[row] = (d01 <= GAPV) || (i1 != cls);
  }
}

// ---- kernel 2: Gram + hard mining + fused finalize ----
// 4 waves/block, each owns 64 rows (A register-resident). B: 512-col chunk through
// double-buffered 32-col LDS slabs. Pipeline: issue prefetch -> compute -> LDS write
// (vmcnt wait lands HERE, after the MFMAs) -> barrier. grid 32x16 = 2 blocks/CU.
__global__ __launch_bounds__(256, 2) void gram_k(const short* __restrict__ xa,
                                                 const short* __restrict__ xbm,
                                                 const float* __restrict__ sq,
                                                 const int* __restrict__ conf,
                                                 unsigned* __restrict__ emax,
                                                 unsigned* __restrict__ emin,
                                                 unsigned* __restrict__ ctrs,
                                                 float* __restrict__ out) {
  __shared__ short lds[2][SLAB * LDST];
  __shared__ float red[2][4];
  __shared__ int   flag;
  const int tid  = threadIdx.x;
  const int wave = tid >> 6;
  const int lane = tid & 63;
  const int quad = lane >> 4;   // 0..3
  const int m16  = lane & 15;   // 0..15
  const int i0    = blockIdx.x * 256 + wave * 64;
  const int jbase = blockIdx.y * CHUNK;

  unsigned* rg_done = ctrs;                 // [NRG]
  unsigned* g_done  = ctrs + NRG;
  float*    Ssum    = (float*)(ctrs + NRG + 1);
  float*    Csum    = (float*)(ctrs + NRG + 2);

  // A fragments: rows i0 + r*16 + m16, k = ks*32 + quad*8 + e  (80 VGPRs)
  bf16x8 A[4][5];
  #pragma unroll
  for (int r = 0; r < 4; ++r) {
    const short* pa = xa + (size_t)(i0 + r * 16 + m16) * DIM2 + quad * 8;
    #pragma unroll
    for (int ks = 0; ks < 5; ++ks)
      A[r][ks] = *(const bf16x8*)(pa + ks * 32);
  }

  float gmin[4][4], gmax[4][4];
  #pragma unroll
  for (int r = 0; r < 4; ++r)
    #pragma unroll
    for (int q = 0; q < 4; ++q) { gmin[r][q] = INFINITY; gmax[r][q] = -INFINITY; }

  // staging: thread covers col scol (0..31), seg (0..7) -> 5 x 8B pieces
  const int scol = tid >> 3;
  const int seg  = tid & 7;
  const short* gsrc = xbm + (size_t)(jbase + scol) * DIM2 + seg * 4;

  {  // prologue: slab 0 -> lds[0]
    uint2 st[5];
    #pragma unroll
    for (int u = 0; u < 5; ++u) st[u] = *(const uint2*)(gsrc + u * 32);
    short* dst = lds[0] + scol * LDST + seg * 4;
    #pragma unroll
    for (int u = 0; u < 5; ++u) *(uint2*)(dst + u * 32) = st[u];
  }
  __syncthreads();

  #pragma unroll 2
  for (int s = 0; s < NSLAB; ++s) {
    // issue prefetch for slab s+1 (wrapped on last iter -> harmless rewrite of slab0 data)
    const int snext = (s + 1) & (NSLAB - 1);
    const short* gn = gsrc + (size_t)snext * SLAB * DIM2;
    uint2 nx[5];
    #pragma unroll
    for (int u = 0; u < 5; ++u) nx[u] = *(const uint2*)(gn + u * 32);

    // compute from lds[s&1] while prefetch flies
    const short* buf = lds[s & 1];
    #pragma unroll
    for (int jt = 0; jt < SLAB / 16; ++jt) {
      const short* pb = buf + (jt * 16 + m16) * LDST + quad * 8;
      bf16x8 B[5];
      #pragma unroll
      for (int ks = 0; ks < 5; ++ks) B[ks] = *(const bf16x8*)(pb + ks * 32);

      f32x4 acc[4];
      #pragma unroll
      for (int r = 0; r < 4; ++r) acc[r] = (f32x4){0.f, 0.f, 0.f, 0.f};
      #pragma unroll
      for (int ks = 0; ks < 5; ++ks)
        #pragma unroll
        for (int r = 0; r < 4; ++r)
          acc[r] = __builtin_amdgcn_mfma_f32_16x16x32_bf16(A[r][ks], B[ks], acc[r], 0, 0, 0);

      #pragma unroll
      for (int r = 0; r < 4; ++r)
        #pragma unroll
        for (int q = 0; q < 4; ++q) {
          gmin[r][q] = fminf(gmin[r][q], acc[r][q]);
          gmax[r][q] = fmaxf(gmax[r][q], acc[r][q]);
        }
    }

    // store prefetched slab into the other buffer (vmcnt wait lands here, post-MFMA)
    short* dst = lds[(s + 1) & 1] + scol * LDST + seg * 4;
    #pragma unroll
    for (int u = 0; u < 5; ++u) *(uint2*)(dst + u * 32) = nx[u];
    __syncthreads();
  }

  // reduce over the 16 cols held across m16 lanes (quad bits preserved)
  #pragma unroll
  for (int m = 1; m <= 8; m <<= 1)
    #pragma unroll
    for (int r = 0; r < 4; ++r)
      #pragma unroll
      for (int q = 0; q < 4; ++q) {
        gmin[r][q] = fminf(gmin[r][q], __shfl_xor(gmin[r][q], m, 64));
        gmax[r][q] = fmaxf(gmax[r][q], __shfl_xor(gmax[r][q], m, 64));
      }

  if (m16 == 0) {
    #pragma unroll
    for (int r = 0; r < 4; ++r)
      #pragma unroll
      for (int q = 0; q < 4; ++q) {
        const int row = i0 + r * 16 + quad * 4 + q;
        // hardest positive: max_same(sq_j - 2dot) = (128 - 2*gmin) - 2048
        atomicMax(&emax[row], fenc(C0 - 2.f * gmin[r][q] - BIAS));
        // hardest negative: min_diff(sq_j - 2dot) = 128 - 2*gmax
        atomicMin(&emin[row], fenc(C0 - 2.f * gmax[r][q]));
      }
  }

  // ---- fused finalize: 16th block of this rowgroup handles its 256 rows ----
  __syncthreads();   // all atomics drained (vmcnt) before counter bump
  if (tid == 0) {
    __threadfence();
    flag = (atomicAdd(&rg_done[blockIdx.x], 1u) == NCHUNK - 1u);
  }
  __syncthreads();
  if (!flag) return;

  const int row = blockIdx.x * 256 + tid;
  float ps = 0.f, pc = 0.f;
  if (conf[row]) {
    const float hi = fdec(atomicMax(&emax[row], 0u));           // identity: fenc >= 0x007FFFFF
    const float lo = fdec(atomicMin(&emin[row], 0xFFFFFFFFu));  // identity
    const float ap = sqrtf(fmaxf(sq[row] + hi, 1e-12f));
    const float an = sqrtf(fmaxf(sq[row] + lo, 1e-12f));
    ps = fmaxf(ap - an, 0.f);
    pc = 1.f;
  }
  #pragma unroll
  for (int m = 1; m < 64; m <<= 1) {
    ps += __shfl_xor(ps, m, 64);
    pc += __shfl_xor(pc, m, 64);
  }
  if (lane == 0) { red[0][wave] = ps; red[1][wave] = pc; }
  __syncthreads();
  if (tid == 0) {
    float S = red[0][0] + red[0][1] + red[0][2] + red[0][3];
    float C = red[1][0] + red[1][1] + red[1][2] + red[1][3];
    atomicAdd(Ssum, S);
    atomicAdd(Csum, C);
    __threadfence();
    if (atomicAdd(g_done, 1u) == NRG - 1u) {
      const float St = atomicAdd(Ssum, 0.f);
      const float Ct = atomicAdd(Csum, 0.f);
      out[0] = (Ct > 0.f) ? (St / fmaxf(Ct, 1.f)) : 0.f;
    }
  }
}

extern "C" void kernel_launch(void* const* d_in, const int* in_sizes, int n_in,
                              void* d_out, int out_size, void* d_ws, size_t ws_size,
                              hipStream_t stream) {
  const float* x    = (const float*)d_in[0];
  const float* pred = (const float*)d_in[1];
  const int*   tgt  = (const int*)d_in[2];
  float* out = (float*)d_out;

  char* w = (char*)d_ws;
  const size_t arr_bytes = (size_t)NROWS * DIM2 * 2;  // 2.56 MiB each
  short*    xa   = (short*)w;
  short*    xbm  = (short*)(w + arr_bytes);
  float*    sq   = (float*)(w + 2 * arr_bytes);
  unsigned* emax = (unsigned*)(w + 2 * arr_bytes + (size_t)NROWS * 4);
  unsigned* emin = (unsigned*)(w + 2 * arr_bytes + (size_t)NROWS * 8);
  int*      conf = (int*)(w + 2 * arr_bytes + (size_t)NROWS * 12);
  unsigned* ctrs = (unsigned*)(w + 2 * arr_bytes + (size_t)NROWS * 16);  // rg_done[32], g_done, Ssum, Csum

  hipLaunchKernelGGL(prep_k, dim3(NROWS / 4), dim3(256), 0, stream,
                     x, tgt, pred, xa, xbm, sq, emax, emin, conf, ctrs);
  hipLaunchKernelGGL(gram_k, dim3(NRG, NCHUNK), dim3(256), 0, stream,
                     xa, xbm, sq, conf, emax, emin, ctrs, out);
}